// Round 11
// baseline (427.816 us; speedup 1.0000x reference)
//
#include <hip/hip_runtime.h>

typedef short bf16x8 __attribute__((ext_vector_type(8)));
typedef float f32x4 __attribute__((ext_vector_type(4)));

#define NROWS 131072L
#define DIN 1024
#define DEMB 512
#define NEXT 640   // extended B rows: 512 emb + 34 folded-head + zero tail

// f32 -> bf16 RNE bit-twiddle (one-time prep kernels).
__device__ __forceinline__ unsigned short f2bf(float f) {
  unsigned u = __float_as_uint(f);
  u += 0x7FFFu + ((u >> 16) & 1u);
  return (unsigned short)(u >> 16);
}

// Pack two f32 -> two bf16 (round-half-up): 2 adds + 1 v_perm_b32 (R5+-proven).
__device__ __forceinline__ unsigned pkhi(float a, float b) {
  unsigned ua = __float_as_uint(a) + 0x8000u;
  unsigned ub = __float_as_uint(b) + 0x8000u;
  return __builtin_amdgcn_perm(ub, ua, 0x07060302u);
}

__device__ __forceinline__ float softplusf(float v) {
  return fmaxf(v, 0.f) + log1pf(expf(-fabsf(v)));
}

// ---------- kernel 0: Wb (1024x512 f32) -> WbT rows 0..511 (bf16, k-contig) ----------
__global__ __launch_bounds__(256) void wb_transpose(const float* __restrict__ Wb,
                                                    unsigned short* __restrict__ WbT) {
  int g = blockIdx.x * 256 + threadIdx.x;
  int n = g & 511;
  int kb = g >> 9;
  unsigned short tmp[8];
#pragma unroll
  for (int j = 0; j < 8; ++j)
    tmp[j] = f2bf(Wb[(kb * 8 + j) * DEMB + n]);
  uint4 v;
  v.x = (unsigned)tmp[0] | ((unsigned)tmp[1] << 16);
  v.y = (unsigned)tmp[2] | ((unsigned)tmp[3] << 16);
  v.z = (unsigned)tmp[4] | ((unsigned)tmp[5] << 16);
  v.w = (unsigned)tmp[6] | ((unsigned)tmp[7] << 16);
  *(uint4*)(WbT + (long)n * DIN + kb * 8) = v;
}

// ---------- kernel 0b: zero rows 546..639 of WbT_ext ----------
__global__ void zero_tail(unsigned* __restrict__ p) {
  p[blockIdx.x * 256 + threadIdx.x] = 0u;
}

// ---------- kernel 0c: WbT rows 512..545 = (Wb @ W34)^T  (head-weight fold) ----------
__global__ __launch_bounds__(256) void wfold_rows(const float* __restrict__ Wb,
                                                  const float* __restrict__ Wp,
                                                  const float* __restrict__ Ws,
                                                  unsigned short* __restrict__ WbT) {
  int w = threadIdx.x >> 6, lane = threadIdx.x & 63;
  int k = blockIdx.x * 4 + w;
  if (lane >= 34) return;
  const float* src;
  if (lane < 2) src = Wp + lane;
  else { int s = (lane - 2) >> 1; src = Ws + s * 1024 + (lane & 1); }
  const float* wrow = Wb + (long)k * DEMB;
  float acc = 0.f;
#pragma unroll 8
  for (int d = 0; d < DEMB; ++d) acc = fmaf(wrow[d], src[2 * d], acc);
  WbT[(long)(512 + lane) * DIN + k] = f2bf(acc);
}

// ---------- kernel 0d: bfold[j] = bb @ W34[:,j] + bias34[j] ----------
__global__ void bfold_k(const float* __restrict__ bb, const float* __restrict__ Wp,
                        const float* __restrict__ bp, const float* __restrict__ Ws,
                        const float* __restrict__ bs, float* __restrict__ bf) {
  int j = threadIdx.x;
  if (j >= 34) return;
  const float* src; float bias;
  if (j < 2) { src = Wp + j; bias = bp[j]; }
  else { int s = (j - 2) >> 1; src = Ws + s * 1024 + (j & 1); bias = bs[s * 2 + (j & 1)]; }
  float acc = bias;
  for (int d = 0; d < DEMB; ++d) acc = fmaf(bb[d], src[2 * d], acc);
  bf[j] = acc;
}

#define SB __builtin_amdgcn_sched_barrier(0)

// ---------- kernel 1: fused GEMM, multi-phase (T3+T4+T5) ----------
// BM=256 BN=128 BK=64, 8 waves (wave-tile 64x64, grid 4m x 2n), 512 thr.
// 2 phases/K-tile (ks0,ks1). Counted vmcnt only: A f32 loads get 3 phases of
// flight (vmcnt(10) at next tile's phase B); B gload_lds 2 phases (vmcnt(8)
// at phase-B end). LDS 96KB: As dbuf 2x32K (bf16 after pkhi), Bs dbuf 2x16K.
__global__ __launch_bounds__(512, 2) void gemm_fused(
    const float* __restrict__ x, const unsigned short* __restrict__ wbt,
    const float* __restrict__ bb, const int* __restrict__ sid,
    const float* __restrict__ bfold, float* __restrict__ out) {
  __shared__ __align__(16) char SM[98304];
  char* const As0 = SM;            // 32 KB: 256 rows x 128B (64 bf16)
  char* const As1 = SM + 32768;
  char* const Bs0 = SM + 65536;    // 16 KB: 128 rows x 128B
  char* const Bs1 = SM + 81920;

  const int t = threadIdx.x;                 // 0..511
  const int lane = t & 63;
  const int wid = t >> 6;                    // 0..7
  const int wm = wid >> 1, wn = wid & 1;     // 4m x 2n wave grid

  // XCD swizzle: 2560 blocks (%8==0); 5 consecutive swz share one mtile/XCD.
  const int bid = blockIdx.x;
  const int swz = (bid & 7) * 320 + (bid >> 3);
  const int mtile = swz / 5;
  const int ntile = swz - mtile * 5;         // 0..3 emb, 4 = head
  const long m0 = (long)mtile * 256;
  const int n0 = ntile * 128;

  // ---- A staging: thread owns k-granule (t&7) of row (t>>3)+p*64, p=0..3 ----
  // LDS phys granule = (t&7) ^ ((t>>3)&7) on 128B rows (2-way-free swizzle).
  const int abyte = (t >> 3) * 128 + ((((t & 7) ^ ((t >> 3) & 7)) << 4));  // +p*8192
  const float* xbase = x + (m0 + (t >> 3)) * DIN + (t & 7) * 8;

  // ---- B staging (gload_lds, linear dest + pre-swizzled source) ----
  // dest row = i*64 + (t>>3), phys g = t&7 -> src granule = (t&7)^((t>>3)&7)
  const unsigned short* bsrc =
      wbt + (long)(n0 + (t >> 3)) * DIN + ((t & 7) ^ ((t >> 3) & 7)) * 8;

  // ---- fragment reads: phys = (ks*4+lg) ^ (l15&7); ks=1 is byte^64 ----
  const int l15 = lane & 15, lg = lane >> 4;
  const int kgo = ((lg ^ (l15 & 7)) << 4);
  const int arow = (wm * 64 + l15) * 128;    // + mi*2048
  const int brow = (wn * 64 + l15) * 128;    // + ni*2048

  f32x4 acc[4][4] = {};
  float4 aE[8], aO[8];                       // A reg bufs (tile parity)

  auto stageB = [&](char* Bw, int k0) {      // 2 x gload_lds 16B
#pragma unroll
    for (int i = 0; i < 2; ++i) {
      const unsigned short* gp = bsrc + (long)i * 64 * DIN + k0;
      __builtin_amdgcn_global_load_lds(
          (const __attribute__((address_space(1))) void*)gp,
          (__attribute__((address_space(3))) void*)(Bw + i * 8192 + wid * 1024),
          16, 0, 0);
    }
  };
  auto loadA = [&](float4* d, int k0) {      // 8 x dwordx4 f32
#pragma unroll
    for (int p = 0; p < 4; ++p) {
      const float* rp = xbase + (long)p * 64 * DIN + k0;
      d[2 * p]     = *(const float4*)rp;
      d[2 * p + 1] = *(const float4*)(rp + 4);
    }
  };
  auto writeA = [&](char* Aw, const float4* d) {   // 4 x ds_write_b128 (pkhi)
#pragma unroll
    for (int p = 0; p < 4; ++p) {
      uint4 v;
      v.x = pkhi(d[2 * p].x,     d[2 * p].y);
      v.y = pkhi(d[2 * p].z,     d[2 * p].w);
      v.z = pkhi(d[2 * p + 1].x, d[2 * p + 1].y);
      v.w = pkhi(d[2 * p + 1].z, d[2 * p + 1].w);
      *(uint4*)(Aw + abyte + p * 8192) = v;
    }
  };
  auto compute = [&](const char* Ac, const char* Bc, int ks) {  // 8 ds_read + 16 MFMA
    const int ko = kgo ^ (ks << 6);
    bf16x8 af[4], bfv[4];
#pragma unroll
    for (int i = 0; i < 4; ++i) {
      af[i]  = *(const bf16x8*)(Ac + arow + i * 2048 + ko);
      bfv[i] = *(const bf16x8*)(Bc + brow + i * 2048 + ko);
    }
    SB;
    asm volatile("s_waitcnt lgkmcnt(0)" ::: "memory");
    SB;
    __builtin_amdgcn_s_setprio(1);
#pragma unroll
    for (int mi = 0; mi < 4; ++mi)
#pragma unroll
      for (int ni = 0; ni < 4; ++ni)
        acc[mi][ni] = __builtin_amdgcn_mfma_f32_16x16x32_bf16(af[mi], bfv[ni],
                                                             acc[mi][ni], 0, 0, 0);
    __builtin_amdgcn_s_setprio(0);
  };

  // ---- prologue: A(0)/B(0) staged+drained into slot0; A(1) in flight ----
  stageB(Bs0, 0);
  loadA(aE, 0);                               // A(0) -> aE (parity 0)
  SB; asm volatile("s_waitcnt vmcnt(0)" ::: "memory"); SB;
  writeA(As0, aE);
  loadA(aO, 64);                              // A(1) -> aO, stays in flight
  asm volatile("s_waitcnt lgkmcnt(0)" ::: "memory");
  __builtin_amdgcn_s_barrier();

  // ---- main loop: tiles 0..13 (pairs), per tile 2 phases ----
#pragma unroll 1
  for (int tt = 0; tt < 14; tt += 2) {
    // EVEN tile tt: compute As0/Bs0; stage B(tt+1)->Bs1; A(tt+2)->aE; write aO->As1
    stageB(Bs1, (tt + 1) * 64);
    loadA(aE, (tt + 2) * 64);
    compute(As0, Bs0, 0);                    // phase A
    __builtin_amdgcn_s_barrier();
    SB; asm volatile("s_waitcnt vmcnt(10)" ::: "memory"); SB;   // A(tt+1) regs landed
    writeA(As1, aO);
    compute(As0, Bs0, 1);                    // phase B (lgkm0 inside covers writes)
    SB; asm volatile("s_waitcnt vmcnt(8) lgkmcnt(0)" ::: "memory"); SB;  // B(tt+1) in LDS
    __builtin_amdgcn_s_barrier();
    // ODD tile tt+1: compute As1/Bs1; stage B(tt+2)->Bs0; A(tt+3)->aO; write aE->As0
    stageB(Bs0, (tt + 2) * 64);
    loadA(aO, (tt + 3) * 64);
    compute(As1, Bs1, 0);
    __builtin_amdgcn_s_barrier();
    SB; asm volatile("s_waitcnt vmcnt(10)" ::: "memory"); SB;
    writeA(As0, aE);
    compute(As1, Bs1, 1);
    SB; asm volatile("s_waitcnt vmcnt(8) lgkmcnt(0)" ::: "memory"); SB;
    __builtin_amdgcn_s_barrier();
  }

  // ---- tail: tile 14 (even; no A-issue), tile 15 (no issues) ----
  stageB(Bs1, 15 * 64);                      // B(15)
  compute(As0, Bs0, 0);
  __builtin_amdgcn_s_barrier();
  SB; asm volatile("s_waitcnt vmcnt(2)" ::: "memory"); SB;      // A(15) regs landed
  writeA(As1, aO);
  compute(As0, Bs0, 1);
  SB; asm volatile("s_waitcnt vmcnt(0) lgkmcnt(0)" ::: "memory"); SB;
  __builtin_amdgcn_s_barrier();
  compute(As1, Bs1, 0);                      // tile 15
  compute(As1, Bs1, 1);

  // ---- epilogue ----
  if (ntile < 4) {
    const int colg = n0 + wn * 64 + l15;
    float bbv[4];
#pragma unroll
    for (int ni = 0; ni < 4; ++ni) bbv[ni] = bb[colg + ni * 16];
#pragma unroll
    for (int mi = 0; mi < 4; ++mi) {
      const long rbase = m0 + wm * 64 + mi * 16 + lg * 4;
#pragma unroll
      for (int ni = 0; ni < 4; ++ni)
#pragma unroll
        for (int r = 0; r < 4; ++r)
          out[(rbase + r) * DEMB + colg + ni * 16] = acc[mi][ni][r] + bbv[ni];
    }
  } else {
    // head tile: acc cols 0..33 are x@Wfold; gather selected cols per row
    __syncthreads();
    float* hl = (float*)SM;                  // [256][35] f32 = 35 KB overlay
    if (wn == 0) {
#pragma unroll
      for (int ni = 0; ni < 3; ++ni) {
#pragma unroll
        for (int mi = 0; mi < 4; ++mi)
#pragma unroll
          for (int r = 0; r < 4; ++r) {
            int row = wm * 64 + mi * 16 + lg * 4 + r;
            int col = l15 + ni * 16;
            if (col < 35) hl[row * 35 + col] = acc[mi][ni][r];
          }
      }
    }
    __syncthreads();
    if (t < 256) {
      const long row = m0 + t;
      const int s = sid[row];
      const float v0 = hl[t * 35 + 0] + bfold[0];
      const float v1 = hl[t * 35 + 1] + bfold[1];
      const float v2 = hl[t * 35 + 2 + 2 * s] + bfold[2 + 2 * s];
      const float v3 = hl[t * 35 + 3 + 2 * s] + bfold[3 + 2 * s];
      float* hp = out + NROWS * DEMB;
      hp[row] = v0;
      hp[NROWS + row] = softplusf(v1) + 0.001f;
      hp[2 * NROWS + row] = v2;
      hp[3 * NROWS + row] = softplusf(v3) + 0.001f;
    }
  }
}

extern "C" void kernel_launch(void* const* d_in, const int* in_sizes, int n_in,
                              void* d_out, int out_size, void* d_ws, size_t ws_size,
                              hipStream_t stream) {
  const float* x  = (const float*)d_in[0];
  const int* sid  = (const int*)d_in[1];
  const float* Wb = (const float*)d_in[2];
  const float* bb = (const float*)d_in[3];
  const float* Wp = (const float*)d_in[4];
  const float* bp = (const float*)d_in[5];
  const float* Ws = (const float*)d_in[6];
  const float* bs = (const float*)d_in[7];
  float* out = (float*)d_out;
  unsigned short* WbT = (unsigned short*)d_ws;            // 640*1024 bf16 = 1.25 MiB
  float* bfoldp = (float*)(WbT + (long)NEXT * DIN);       // 34 f32

  wb_transpose<<<256, 256, 0, stream>>>(Wb, WbT);
  zero_tail<<<188, 256, 0, stream>>>((unsigned*)(WbT + 546 * DIN));
  wfold_rows<<<256, 256, 0, stream>>>(Wb, Wp, Ws, WbT);
  bfold_k<<<1, 64, 0, stream>>>(bb, Wp, bp, Ws, bs, bfoldp);
  gemm_fused<<<2560, 512, 0, stream>>>(x, WbT, bb, sid, bfoldp, out);
}